// Round 14
// baseline (1276.728 us; speedup 1.0000x reference)
//
#include <hip/hip_runtime.h>

typedef unsigned short u16;
typedef unsigned int u32;
typedef __attribute__((ext_vector_type(8))) short s8v;      // 8x16-bit
typedef __attribute__((ext_vector_type(8))) _Float16 h8v;   // 8 fp16
typedef __attribute__((ext_vector_type(4))) float f4v;      // C/D frag

#define NN 100000
#define MROW 100096
#define EE 500000
#define GG 16
#define APIT 152      // A-source row pitch (u16, fp16): H, u, U ; U cols 150/151 = degree
#define WFM 30720     // frag-order weight mat size (u16) = 192 rows x 160 k
#define SCB 1024      // scan elems per block
#define SNB 98        // ceil(NN/SCB)

__device__ __forceinline__ u16 f2h(float x){ union{u16 u;_Float16 f;}c; c.f=(_Float16)x; return c.u; }
__device__ __forceinline__ float h2f(u16 b){ union{u16 u;_Float16 f;}c; c.u=b; return (float)c.f; }

#define GLOAD_LDS(gp, lp) \
    __builtin_amdgcn_global_load_lds((const __attribute__((address_space(1))) void*)(gp), \
                                     (__attribute__((address_space(3))) void*)(lp), 16, 0, 0)

// frag-order weight index: mat-local. row<192, k<160.
__device__ __forceinline__ size_t widx(int row, int k){
    return (size_t)(((row>>4)*5 + (k>>5))*512) + ((((k>>3)&3)*16 + (row&15))*8) + (k&7);
}

// ---------------- staging (coalesced, swizzled) ----------------
template<int NI>
__device__ __forceinline__ void stage(const u16* base, const int (&off)[NI], int koff,
                                      const int (&lds)[NI], u16* dst){
#pragma unroll
    for (int i=0;i<NI;i++) GLOAD_LDS(base+off[i]+koff, dst+lds[i]);
}

__device__ __forceinline__ void lda64(const u16* lA_, const int (&aF)[2][4], s8v (&a)[2][4]){
#pragma unroll
    for (int ks=0;ks<2;ks++)
#pragma unroll
        for (int mi=0;mi<4;mi++) a[ks][mi] = *(const s8v*)(lA_+aF[ks][mi]);
}
__device__ __forceinline__ void lda32(const u16* lA_, const int (&aF)[4], s8v (&a)[4]){
#pragma unroll
    for (int mi=0;mi<4;mi++) a[mi] = *(const s8v*)(lA_+aF[mi]);
}

// direct frag-order W loads + MFMA
__device__ __forceinline__ void mf3d(const s8v (&af)[4], const u16* wp,
                                     f4v (&X)[4], f4v (&Y)[4], f4v (&Z)[4]){
    h8v w0 = *(const h8v*)(wp);
    h8v w1 = *(const h8v*)(wp + WFM);
    h8v w2 = *(const h8v*)(wp + 2*WFM);
#pragma unroll
    for (int mi=0;mi<4;mi++){
        X[mi]=__builtin_amdgcn_mfma_f32_16x16x32_f16(*(const h8v*)&af[mi],w0,X[mi],0,0,0);
        Y[mi]=__builtin_amdgcn_mfma_f32_16x16x32_f16(*(const h8v*)&af[mi],w1,Y[mi],0,0,0);
        Z[mi]=__builtin_amdgcn_mfma_f32_16x16x32_f16(*(const h8v*)&af[mi],w2,Z[mi],0,0,0);
    }
}
__device__ __forceinline__ void mf2d(const s8v (&af)[4], const u16* wp,
                                     f4v (&X)[4], f4v (&Y)[4]){
    h8v w0 = *(const h8v*)(wp);
    h8v w1 = *(const h8v*)(wp + WFM);
#pragma unroll
    for (int mi=0;mi<4;mi++){
        X[mi]=__builtin_amdgcn_mfma_f32_16x16x32_f16(*(const h8v*)&af[mi],w0,X[mi],0,0,0);
        Y[mi]=__builtin_amdgcn_mfma_f32_16x16x32_f16(*(const h8v*)&af[mi],w1,Y[mi],0,0,0);
    }
}

// ---------------- edge-MLP layer 1 (both sets), single stage-round ----------------
__global__ __launch_bounds__(256,3) void k_ugemm2(const u16* __restrict__ H,
    const u16* __restrict__ W1f,   // 2 frag-order fp16 mats: [set0|set1]
    const float* __restrict__ b1t0, const float* __restrict__ b1t1,
    u16* __restrict__ u0, u16* __restrict__ u1)
{
    __shared__ u16 lAa[64*64], lAb[64*64], lAc[64*32];
    int tid=threadIdx.x, wv=tid>>6, lane=tid&63, lr=lane&15, quad=lane>>4;
    int m0=blockIdx.x*64, n0=blockIdx.y*64;
    int aL64[2], aO64[2];
#pragma unroll
    for (int i=0;i<2;i++){ int s=tid+i*256, row=s>>3, q8=((s&7)^(row&7))<<3;
        aL64[i]=s<<3; aO64[i]=(m0+row)*APIT+q8; }
    int aL32[1], aO32[1];
    { int s=tid, row=s>>2, q8=((s&3)^(row&3))<<3; aL32[0]=s<<3; aO32[0]=(m0+row)*APIT+q8; }
    int aF64[2][4], aF32[4];
#pragma unroll
    for (int ks=0;ks<2;ks++)
#pragma unroll
        for (int mi=0;mi<4;mi++){ int row=mi*16+lr, ph=(ks*4+quad)^(row&7); aF64[ks][mi]=row*64+ph*8; }
#pragma unroll
    for (int mi=0;mi<4;mi++){ int row=mi*16+lr, ph=quad^(row&3); aF32[mi]=row*32+ph*8; }
    int jw = blockIdx.y*4 + wv;
    const u16* Wp = W1f + (size_t)(jw*5)*512 + lane*8;

    f4v a0[4]={}, a1[4]={};
    s8v a[2][4]; s8v a32[4];
    // single stage round: whole 64x160 A tile
    stage<2>(H,aO64,0,  aL64,lAa);
    stage<2>(H,aO64,64, aL64,lAb);
    stage<1>(H,aO32,128,aL32,lAc);
    __syncthreads();
    lda64(lAa,aF64,a);
#pragma unroll
    for (int ks=0;ks<2;ks++) mf2d(a[ks], Wp + ks*512, a0,a1);
    lda64(lAb,aF64,a);
#pragma unroll
    for (int ks=0;ks<2;ks++) mf2d(a[ks], Wp + (2+ks)*512, a0,a1);
    lda32(lAc,aF32,a32);
    mf2d(a32, Wp + 4*512, a0,a1);

    int c = n0 + wv*16 + lr;
    if (c < 152){
        float bb0=b1t0[c], bb1=b1t1[c];
#pragma unroll
        for (int mi=0;mi<4;mi++)
#pragma unroll
            for (int reg=0;reg<4;reg++){
                int r = m0 + mi*16 + quad*4 + reg;
                if (r >= NN) continue;
                float v0=a0[mi][reg]+bb0; v0 = v0>0.f ? v0 : 0.01f*v0;
                float v1=a1[mi][reg]+bb1; v1 = v1>0.f ? v1 : 0.01f*v1;
                if (c>=150){ v0=0.f; v1=0.f; }
                u0[(size_t)r*APIT+c]=f2h(v0);
                u1[(size_t)r*APIT+c]=f2h(v1);
            }
    }
}

// ---------------- fused GRU mega-kernel: U0+U1+H staged together per round ----------------
__global__ __launch_bounds__(256,3) void k_mega(const u16* __restrict__ H,
    const u16* __restrict__ U0, const u16* __restrict__ U1,
    const u16* __restrict__ Cf,   // 6 frag-order mats: [s][gate r,z,n] (deg cols folded)
    const u16* __restrict__ Whf,  // 3 frag-order mats: Whh gates r,z,n
    const float* __restrict__ tb, u16* __restrict__ Hn)
{
    __shared__ u16 lU0[64*64], lU1[64*64], lH[64*64];
    int tid=threadIdx.x, wv=tid>>6, lane=tid&63, lr=lane&15, quad=lane>>4;
    int m0=blockIdx.x*64, n0=blockIdx.y*64;
    int aL64[2], aO64[2];
#pragma unroll
    for (int i=0;i<2;i++){ int s=tid+i*256, row=s>>3, q8=((s&7)^(row&7))<<3;
        aL64[i]=s<<3; aO64[i]=(m0+row)*APIT+q8; }
    int aL32[1], aO32[1];
    { int s=tid, row=s>>2, q8=((s&3)^(row&3))<<3; aL32[0]=s<<3; aO32[0]=(m0+row)*APIT+q8; }
    int aF64[2][4], aF32[4];
#pragma unroll
    for (int ks=0;ks<2;ks++)
#pragma unroll
        for (int mi=0;mi<4;mi++){ int row=mi*16+lr, ph=(ks*4+quad)^(row&7); aF64[ks][mi]=row*64+ph*8; }
#pragma unroll
    for (int mi=0;mi<4;mi++){ int row=mi*16+lr, ph=quad^(row&3); aF32[mi]=row*32+ph*8; }
    int jw = blockIdx.y*4 + wv;
    int laneoff = lane*8;
    const u16* Wp0 = Cf + (size_t)(jw*5)*512 + laneoff;            // set0 gates
    const u16* Wp1 = Cf + 3*WFM + (size_t)(jw*5)*512 + laneoff;    // set1 gates
    const u16* WpH = Whf + (size_t)(jw*5)*512 + laneoff;           // h gates

    f4v aR[4]={}, aZ[4]={}, aI[4]={}, aHh[4]={};
    s8v a[2][4]; s8v a32[4];
#pragma unroll
    for (int kc=0;kc<2;kc++){
        int koff=kc*64;
        if (kc) __syncthreads();            // protect LDS overwrite
        stage<2>(U0,aO64,koff,aL64,lU0);
        stage<2>(U1,aO64,koff,aL64,lU1);
        stage<2>(H, aO64,koff,aL64,lH);
        __syncthreads();
        lda64(lU0,aF64,a);
#pragma unroll
        for (int ks=0;ks<2;ks++) mf3d(a[ks], Wp0 + (kc*2+ks)*512, aR,aZ,aI);
        lda64(lU1,aF64,a);
#pragma unroll
        for (int ks=0;ks<2;ks++) mf3d(a[ks], Wp1 + (kc*2+ks)*512, aR,aZ,aI);
        lda64(lH,aF64,a);
#pragma unroll
        for (int ks=0;ks<2;ks++) mf3d(a[ks], WpH + (kc*2+ks)*512, aR,aZ,aHh);
    }
    __syncthreads();
    stage<1>(U0,aO32,128,aL32,lU0);
    stage<1>(U1,aO32,128,aL32,lU1);
    stage<1>(H, aO32,128,aL32,lH);
    __syncthreads();
    lda32(lU0,aF32,a32); mf3d(a32, Wp0 + 4*512, aR,aZ,aI);
    lda32(lU1,aF32,a32); mf3d(a32, Wp1 + 4*512, aR,aZ,aI);
    lda32(lH, aF32,a32); mf3d(a32, WpH + 4*512, aR,aZ,aHh);

    // ---- GRU epilogue ----
    int c = n0 + wv*16 + lr;
    if (c < 152){
        float bR=tb[c], bZ=tb[160+c], bI=tb[320+c], bHn=tb[480+c];
#pragma unroll
        for (int mi=0;mi<4;mi++)
#pragma unroll
            for (int reg=0;reg<4;reg++){
                int r = m0 + mi*16 + quad*4 + reg;
                if (r >= NN) continue;
                float pr=aR[mi][reg]+bR, pz=aZ[mi][reg]+bZ, pi=aI[mi][reg]+bI, ph_=aHh[mi][reg]+bHn;
                float rg = 1.f/(1.f+__expf(-pr));
                float zg = 1.f/(1.f+__expf(-pz));
                float e2 = __expf(2.f*(pi + rg*ph_));
                float n  = 1.f - 2.f/(e2+1.f);
                float hold = h2f(H[(size_t)r*APIT+c]);
                float o = (1.f-zg)*n + zg*hold;
                if (c>=150) o = 0.f;
                Hn[(size_t)r*APIT+c] = f2h(o);
            }
    }
}

// ---------------- prep kernels (write frag-order) ----------------
__global__ void k_cast16(const float* __restrict__ src, int rowoff, u16* __restrict__ dst){
    int idx = blockIdx.x*256 + threadIdx.x;     // 192*160
    if (idx >= 192*160) return;
    int r = idx/160, c = idx - r*160;
    float x = (r<150 && c<150) ? src[(size_t)(rowoff+r)*150 + c] : 0.f;
    dst[widx(r,c)] = f2h(x);
}

// composite C[s*3+g] = Wih_g @ W2_s (cols 0..149); col150(s=0)/col151(s=1) = Wih_g @ b2_s ; fp16
__global__ void k_comp(const float* __restrict__ Wih, const float* __restrict__ W2_0,
                       const float* __restrict__ W2_1, const float* __restrict__ b2_0,
                       const float* __restrict__ b2_1, u16* __restrict__ Cf){
    int idx = blockIdx.x*256 + threadIdx.x;     // 6*192*160
    if (idx >= 6*192*160) return;
    int mat = idx/(192*160), rem = idx - mat*(192*160);
    int o = rem/160, c = rem - o*160;
    int s = mat/3, g = mat - s*3;
    float v = 0.f;
    if (o < 150){
        const float* wrow = Wih + (size_t)(g*150+o)*150;
        if (c < 150){
            const float* W2 = s ? W2_1 : W2_0;
            for (int j=0;j<150;j++) v += wrow[j] * W2[(size_t)j*150 + c];
        } else if (c==150 && s==0){
            for (int j=0;j<150;j++) v += wrow[j] * b2_0[j];
        } else if (c==151 && s==1){
            for (int j=0;j<150;j++) v += wrow[j] * b2_1[j];
        }
    }
    Cf[(size_t)mat*WFM + widx(o,c)] = f2h(v);
}

__global__ void k_tabs(const float* bih,const float* bhh,
                       const float* b1_0,const float* b1_1,
                       float* tb, float* b1t0, float* b1t1){
    int idx = blockIdx.x*256 + threadIdx.x;     // 6*160
    if (idx >= 6*160) return;
    int t = idx/160, c = idx - t*160;
    float v = 0.f;
    if (c < 150){
        if (t==0) v = bih[c]+bhh[c];
        else if (t==1) v = bih[150+c]+bhh[150+c];
        else if (t==2) v = bih[300+c];
        else if (t==3) v = bhh[300+c];
        else if (t==4) v = b1_0[c];
        else v = b1_1[c];
    }
    if (t<4) tb[t*160+c]=v;
    else if (t==4) b1t0[c]=v;
    else b1t1[c]=v;
}

__global__ void k_padfc1(const float* __restrict__ s, float* __restrict__ d){
    int idx = blockIdx.x*256 + threadIdx.x;     // 80*160
    if (idx >= 80*160) return;
    int r = idx/160, c = idx - r*160;
    d[idx] = (c<151) ? s[r*151 + c] : 0.f;
}

__global__ void k_inith(const float* __restrict__ nodes, u16* __restrict__ H){
    int idx = blockIdx.x*256 + threadIdx.x;     // NN*152
    if (idx >= NN*152) return;
    int m = idx/152, c = idx - m*152;
    float x = (c<150) ? nodes[(size_t)m*150 + c] : 0.f;
    H[(size_t)m*APIT + c] = f2h(x);
}

// ---------------- CSR build (multi-block scan; grid.y = edge set) ----------------
__global__ void k_hist2(const int* __restrict__ e0, const int* __restrict__ e1, int* __restrict__ hist){
    int e = blockIdx.x*256 + threadIdx.x;
    if (e >= EE) return;
    const int* ed = blockIdx.y ? e1 : e0;
    atomicAdd(&hist[blockIdx.y*NN + ed[2*e]], 1);
}

__global__ __launch_bounds__(256) void k_psum(const int* __restrict__ hist, int* __restrict__ part){
    int b = blockIdx.x, y = blockIdx.y, t = threadIdx.x;
    const int* cnt = hist + y*NN;
    int i0 = b*SCB + t*4;
    int s = 0;
#pragma unroll
    for (int u=0;u<4;u++){ int i=i0+u; if (i<NN) s += cnt[i]; }
#pragma unroll
    for (int o=32;o>0;o>>=1) s += __shfl_down(s,o);
    __shared__ int sd[4];
    if ((t&63)==0) sd[t>>6] = s;
    __syncthreads();
    if (t==0) part[y*128 + b] = sd[0]+sd[1]+sd[2]+sd[3];
}

__global__ __launch_bounds__(128) void k_pscan(int* __restrict__ part, int* __restrict__ off0, int* __restrict__ off1){
    int y = blockIdx.y, t = threadIdx.x;
    __shared__ int sd[128];
    int v = (t < SNB) ? part[y*128 + t] : 0;
    sd[t] = v;
    __syncthreads();
    for (int o=1;o<128;o<<=1){
        int x2 = 0;
        if (t >= o) x2 = sd[t-o];
        __syncthreads();
        if (t >= o) sd[t] += x2;
        __syncthreads();
    }
    if (t < SNB) part[y*128 + t] = sd[t] - v;     // exclusive
    if (t == 127){
        int* off = y ? off1 : off0;
        off[NN] = sd[127];                         // total = EE
    }
}

__global__ __launch_bounds__(256) void k_papply(const int* __restrict__ hist, const int* __restrict__ part,
                                                int* __restrict__ off0, int* __restrict__ off1,
                                                int* __restrict__ cur){
    int b = blockIdx.x, y = blockIdx.y, t = threadIdx.x;
    const int* cnt = hist + y*NN;
    int* off = y ? off1 : off0;
    int* cu  = cur + y*NN;
    int i0 = b*SCB + t*4;
    int v[4]; int s = 0;
#pragma unroll
    for (int u=0;u<4;u++){ int i=i0+u; v[u] = (i<NN) ? cnt[i] : 0; s += v[u]; }
    __shared__ int sd[256];
    sd[t] = s;
    __syncthreads();
    for (int o=1;o<256;o<<=1){
        int x2 = 0;
        if (t >= o) x2 = sd[t-o];
        __syncthreads();
        if (t >= o) sd[t] += x2;
        __syncthreads();
    }
    int excl = part[y*128 + b] + sd[t] - s;
#pragma unroll
    for (int u=0;u<4;u++){
        int i = i0+u;
        if (i<NN){ off[i]=excl; cu[i]=excl; excl += v[u]; }
    }
}

__global__ void k_fill2(const int* __restrict__ e0, const int* __restrict__ e1,
                        int* __restrict__ cur, int* __restrict__ csr0, int* __restrict__ csr1){
    int e = blockIdx.x*256 + threadIdx.x;
    if (e >= EE) return;
    const int* ed = blockIdx.y ? e1 : e0;
    int* csr = blockIdx.y ? csr1 : csr0;
    int dst = ed[2*e], src = ed[2*e+1];
    int pos = atomicAdd(&cur[blockIdx.y*NN + dst], 1);
    csr[pos] = src;
}

// ---------------- gather (unroll-4 for MLP); degree -> cols 150/151 ----------------
__global__ void k_gath2(const u16* __restrict__ u0, const u16* __restrict__ u1,
                        const int* __restrict__ off0, const int* __restrict__ csr0,
                        const int* __restrict__ off1, const int* __restrict__ csr1,
                        u16* __restrict__ U0, u16* __restrict__ U1){
    int d = blockIdx.x*4 + (threadIdx.x>>6);
    if (d >= NN) return;
    int lane = threadIdx.x & 63;
    const u16* u = blockIdx.y ? u1 : u0;
    const int* off = blockIdx.y ? off1 : off0;
    const int* csr = blockIdx.y ? csr1 : csr0;
    u16* U = blockIdx.y ? U1 : U0;
    int e0 = off[d], e1 = off[d+1];
    bool tl = lane < 12;
    float s0=0.f, s1=0.f, t0=0.f, t1=0.f;
    int e = e0;
    for (; e+4 <= e1; e += 4){
        const u32* r0 = (const u32*)(u + (size_t)csr[e]  *APIT);
        const u32* r1 = (const u32*)(u + (size_t)csr[e+1]*APIT);
        const u32* r2 = (const u32*)(u + (size_t)csr[e+2]*APIT);
        const u32* r3 = (const u32*)(u + (size_t)csr[e+3]*APIT);
        u32 v0=r0[lane], v1=r1[lane], v2=r2[lane], v3=r3[lane];
        u32 w0=0, w1=0, w2=0, w3=0;
        if (tl){ w0=r0[64+lane]; w1=r1[64+lane]; w2=r2[64+lane]; w3=r3[64+lane]; }
        s0 += h2f((u16)(v0&0xffffu)) + h2f((u16)(v1&0xffffu)) + h2f((u16)(v2&0xffffu)) + h2f((u16)(v3&0xffffu));
        s1 += h2f((u16)(v0>>16))     + h2f((u16)(v1>>16))     + h2f((u16)(v2>>16))     + h2f((u16)(v3>>16));
        if (tl){
            t0 += h2f((u16)(w0&0xffffu)) + h2f((u16)(w1&0xffffu)) + h2f((u16)(w2&0xffffu)) + h2f((u16)(w3&0xffffu));
            t1 += h2f((u16)(w0>>16))     + h2f((u16)(w1>>16))     + h2f((u16)(w2>>16))     + h2f((u16)(w3>>16));
        }
    }
    for (; e < e1; e++){
        const u32* r = (const u32*)(u + (size_t)csr[e]*APIT);
        u32 v = r[lane];
        s0 += h2f((u16)(v & 0xffffu));
        s1 += h2f((u16)(v >> 16));
        if (tl){
            u32 w = r[64+lane];
            t0 += h2f((u16)(w & 0xffffu));
            t1 += h2f((u16)(w >> 16));
        }
    }
    if (lane == 11){ t0 = (float)(e1-e0); t1 = t0; }   // cols 150,151 = degree
    u32* Ur = (u32*)(U + (size_t)d*APIT);
    Ur[lane] = (u32)f2h(s0) | ((u32)f2h(s1) << 16);
    if (tl) Ur[64+lane] = (u32)f2h(t0) | ((u32)f2h(t1) << 16);
}

// ---------------- segment sum (64-row chunks) + readout ----------------
__global__ void k_seg(const u16* __restrict__ H, const int* __restrict__ gid, float* __restrict__ g){
    int f = threadIdx.x;
    if (f >= 150) return;
    int i0 = blockIdx.x*64;
    int i1 = i0 + 64; if (i1 > NN) i1 = NN;
    float acc = 0.f;
    int cg = gid[i0];
    for (int i=i0; i<i1; i++){
        int gg = gid[i];
        if (gg != cg){ atomicAdd(&g[cg*150+f], acc); acc=0.f; cg=gg; }
        acc += h2f(H[(size_t)i*APIT + f]);
    }
    atomicAdd(&g[cg*150+f], acc);
}

__global__ void k_mlp(const float* __restrict__ g, const float* __restrict__ pt,
                      const float* __restrict__ fc1p, const float* __restrict__ fc1b,
                      const float* __restrict__ fc2W, const float* __restrict__ fc2b,
                      const float* __restrict__ fcLW, const float* __restrict__ fcLb,
                      float* __restrict__ out){
    __shared__ float X[GG][152];
    __shared__ float Y[GG][80];
    __shared__ float Z[GG][80];
    int t = threadIdx.x;
    for (int idx=t; idx<GG*152; idx+=256){
        int gi=idx/152, c=idx-gi*152;
        float v = 0.f;
        if (c < 150){
            float lg = logf(g[gi*150+c]);
            if (lg != lg) lg = 0.f;
            v = fmaxf(lg, 0.f);
        } else if (c == 150) v = pt[gi];
        X[gi][c] = v;
    }
    __syncthreads();
    for (int idx=t; idx<GG*80; idx+=256){
        int gi=idx/80, o=idx-gi*80;
        float acc = fc1b[o];
        for (int k=0;k<151;k++) acc = fmaf(X[gi][k], fc1p[o*160+k], acc);
        Y[gi][o] = acc>0.f ? acc : 0.01f*acc;
    }
    __syncthreads();
    for (int idx=t; idx<GG*80; idx+=256){
        int gi=idx/80, o=idx-gi*80;
        float acc = fc2b[o];
        for (int k=0;k<80;k++) acc = fmaf(Y[gi][k], fc2W[o*80+k], acc);
        Z[gi][o] = acc>0.f ? acc : 0.01f*acc;
    }
    __syncthreads();
    for (int idx=t; idx<GG*10; idx+=256){
        int gi=idx/10, o=idx-gi*10;
        float acc = fcLb[o];
        for (int k=0;k<80;k++) acc = fmaf(Z[gi][k], fcLW[o*80+k], acc);
        out[idx] = acc;
    }
}

// ---------------- host ----------------
extern "C" void kernel_launch(void* const* d_in, const int* in_sizes, int n_in,
                              void* d_out, int out_size, void* d_ws, size_t ws_size,
                              hipStream_t stream) {
    const float* nodes = (const float*)d_in[0];
    const float* pt    = (const float*)d_in[1];
    const float* W1_0 = (const float*)d_in[2];  const float* b1_0 = (const float*)d_in[3];
    const float* W2_0 = (const float*)d_in[4];  const float* b2_0 = (const float*)d_in[5];
    const float* W1_1 = (const float*)d_in[6];  const float* b1_1 = (const float*)d_in[7];
    const float* W2_1 = (const float*)d_in[8];  const float* b2_1 = (const float*)d_in[9];
    const float* Wih = (const float*)d_in[10];  const float* bih = (const float*)d_in[11];
    const float* Whh = (const float*)d_in[12];  const float* bhh = (const float*)d_in[13];
    const float* fc1W = (const float*)d_in[14]; const float* fc1b = (const float*)d_in[15];
    const float* fc2W = (const float*)d_in[16]; const float* fc2b = (const float*)d_in[17];
    const float* fcLW = (const float*)d_in[18]; const float* fcLb = (const float*)d_in[19];
    const int* edges0 = (const int*)d_in[20];
    const int* edges1 = (const int*)d_in[21];
    const int* gid = (const int*)d_in[22];
    float* out = (float*)d_out;

    char* p = (char*)d_ws;
    auto alloc = [&](size_t bytes){ char* r = p; p += (bytes + 255) & ~(size_t)255; return r; };
    u16* XA  = (u16*)alloc((size_t)MROW*APIT*2);
    u16* XB  = (u16*)alloc((size_t)MROW*APIT*2);
    u16* U0  = (u16*)alloc((size_t)MROW*APIT*2);
    u16* U1  = (u16*)alloc((size_t)MROW*APIT*2);
    u16* Yu1 = (u16*)alloc((size_t)MROW*APIT*2);
    u16* W1f = (u16*)alloc((size_t)2*WFM*2);     // [set0|set1] frag-order fp16
    u16* Whf = (u16*)alloc((size_t)3*WFM*2);     // Whh gates r,z,n frag-order fp16
    u16* Cf  = (u16*)alloc((size_t)6*WFM*2);     // composite frag-order fp16
    float* tb   = (float*)alloc(4*160*4);
    float* b1t0 = (float*)alloc(160*4);
    float* b1t1 = (float*)alloc(160*4);
    float* fc1p = (float*)alloc(80*160*4);
    float* gbuf = (float*)alloc(GG*150*4);
    int* off0 = (int*)alloc((NN+1)*4);
    int* off1 = (int*)alloc((NN+1)*4);
    int* cur  = (int*)alloc((size_t)2*NN*4);
    int* hist = (int*)alloc((size_t)2*NN*4);
    int* part = (int*)alloc(2*128*4);
    int* csr0 = (int*)alloc((size_t)EE*4);
    int* csr1 = (int*)alloc((size_t)EE*4);
    (void)alloc(4096);   // tail pad for harmless last-row K-chunk overrun reads

    // ---- prep ----
    k_cast16<<<120, 256, 0, stream>>>(W1_0, 0, W1f);
    k_cast16<<<120, 256, 0, stream>>>(W1_1, 0, W1f + WFM);
    k_cast16<<<120, 256, 0, stream>>>(Whh, 0,   Whf);
    k_cast16<<<120, 256, 0, stream>>>(Whh, 150, Whf + WFM);
    k_cast16<<<120, 256, 0, stream>>>(Whh, 300, Whf + 2*WFM);
    k_comp<<<(6*192*160 + 255)/256, 256, 0, stream>>>(Wih, W2_0, W2_1, b2_0, b2_1, Cf);
    k_tabs<<<4, 256, 0, stream>>>(bih, bhh, b1_0, b1_1, tb, b1t0, b1t1);
    k_padfc1<<<50, 256, 0, stream>>>(fc1W, fc1p);
    k_inith<<<(NN*152 + 255)/256, 256, 0, stream>>>(nodes, XA);

    // ---- CSR (both sets batched via grid.y) ----
    hipMemsetAsync(hist, 0, (size_t)2*NN*sizeof(int), stream);
    dim3 gE((EE+255)/256, 2), gS(SNB, 2), g1(1, 2);
    k_hist2<<<gE, 256, 0, stream>>>(edges0, edges1, hist);
    k_psum<<<gS, 256, 0, stream>>>(hist, part);
    k_pscan<<<g1, 128, 0, stream>>>(part, off0, off1);
    k_papply<<<gS, 256, 0, stream>>>(hist, part, off0, off1, cur);
    k_fill2<<<gE, 256, 0, stream>>>(edges0, edges1, cur, csr0, csr1);

    // ---- message passes ----
    u16* Hc = XA; u16* Hx = XB;
    dim3 gT(MROW/64, 3);
    dim3 gGa((NN+3)/4, 2);
    for (int ps=0; ps<4; ps++){
        u16* yu0 = Hx;   // u scratch for set0 aliases h_next; dead before mega writes Hx
        k_ugemm2<<<gT, 256, 0, stream>>>(Hc, W1f, b1t0, b1t1, yu0, Yu1);
        k_gath2<<<gGa, 256, 0, stream>>>(yu0, Yu1, off0, csr0, off1, csr1, U0, U1);
        k_mega<<<gT, 256, 0, stream>>>(Hc, U0, U1, Cf, Whf, tb, Hx);
        u16* t = Hc; Hc = Hx; Hx = t;
    }

    // ---- readout ----
    hipMemsetAsync(gbuf, 0, GG*150*sizeof(float), stream);
    k_seg<<<(NN+63)/64, 192, 0, stream>>>(Hc, gid, gbuf);
    k_mlp<<<1, 256, 0, stream>>>(gbuf, pt, fc1p, fc1b, fc2W, fc2b, fcLW, fcLb, out);
}